// Round 1
// baseline (7935.329 us; speedup 1.0000x reference)
//
#include <hip/hip_runtime.h>
#include <cstdint>

// LSTM decoder: B=64, S=512, D=512, H=512.
// 8 clusters (blockIdx%8) x 32 WGs; cluster owns 8 batches. WG owns 16 hidden
// units (all 4 gates). W_ih/W_hh slices live in VGPRs as bf16 MFMA A-fragments.
// Per step: gates = bias + W_ih·x_t (pre-barrier, prefetched) + W_hh·h_{t-1}
// (post-barrier). c state is lane-private fp32. h exchanged via 8KB bf16
// fragment buffer in ws + device-scope atomic cluster barrier.

#define SS 512
#define DD 512
#define HH 512

typedef __attribute__((ext_vector_type(8))) short s8;
typedef __attribute__((ext_vector_type(4))) float f4;

__device__ inline short f2bf(float f) {
  unsigned u = __float_as_uint(f);
  u += 0x7fffu + ((u >> 16) & 1u);   // RNE
  return (short)(u >> 16);
}

__device__ inline s8 cvt8(f4 a, f4 b) {
  s8 v;
  v[0]=f2bf(a[0]); v[1]=f2bf(a[1]); v[2]=f2bf(a[2]); v[3]=f2bf(a[3]);
  v[4]=f2bf(b[0]); v[5]=f2bf(b[1]); v[6]=f2bf(b[2]); v[7]=f2bf(b[3]);
  return v;
}

__device__ inline float sigm(float x)  { return 1.f / (1.f + __expf(-x)); }
// tanh via 1 - 2/(e^{2x}+1): safe at both infinities (no NaN).
__device__ inline float tanh_f(float x){ return 1.f - 2.f / (__expf(2.f*x) + 1.f); }

// 32-WG cluster barrier. Release: syncthreads (drains vmcnt) + agent fence
// (buffer_wbl2) + atomic add. Acquire: every thread does one acquire load
// (buffer_inv) so subsequent h reads are fresh across XCDs.
__device__ inline void cluster_barrier(unsigned* cnt, unsigned target) {
  __syncthreads();
  if (threadIdx.x == 0) {
    __threadfence();
    __hip_atomic_fetch_add(cnt, 1u, __ATOMIC_RELAXED, __HIP_MEMORY_SCOPE_AGENT);
    unsigned guard = 0;
    while (__hip_atomic_load(cnt, __ATOMIC_RELAXED, __HIP_MEMORY_SCOPE_AGENT) < target) {
      __builtin_amdgcn_s_sleep(4);
      if (++guard > 10000000u) break;   // anti-hang failsafe
    }
  }
  __syncthreads();
  (void)__hip_atomic_load(cnt, __ATOMIC_ACQUIRE, __HIP_MEMORY_SCOPE_AGENT);
}

__launch_bounds__(256, 1)
__global__ void lstm_kernel(const float* __restrict__ x,   const float* __restrict__ emb,
                            const float* __restrict__ h_n, const float* __restrict__ c_n,
                            const float* __restrict__ W_ih, const float* __restrict__ W_hh,
                            const float* __restrict__ b_ih, const float* __restrict__ b_hh,
                            float* __restrict__ out, char* __restrict__ ws)
{
  const int tid  = threadIdx.x;
  const int wave = tid >> 6, lane = tid & 63;
  const int quad = lane >> 4, n = lane & 15;       // n = batch column (8 real + 8 pad)
  const int c  = blockIdx.x & 7;                   // cluster
  const int wg = blockIdx.x >> 3;                  // 0..31 within cluster

  unsigned* cnt = (unsigned*)(ws + (size_t)c * 128);
  char* hbuf  = ws + 1024;                         // [2][8 clusters][16KB] h fragments
  char* xfrag = ws + 1024 + 2*8*16384;             // [8][512][16KB] x fragments
  char* xfc   = xfrag + (size_t)c * SS * 16384;

  // ---- Phase A1: (emb ++ x[:, :-1]) -> bf16 B-fragment layout, coalesced ----
  {
    int widc = wg*4 + wave;                        // 0..127 warps in cluster
    for (int item = widc; item < 8192; item += 128) {
      int t = item & 511, bl = item >> 9;          // bl = batch col slot 0..15
      s8 v = {0,0,0,0,0,0,0,0};
      if (bl < 8) {
        const float* src = (t == 0) ? (emb + (size_t)(c*8 + bl) * DD)
                                    : (x + ((size_t)(c*8 + bl) * SS + (t-1)) * DD);
        f4 f0 = *(const f4*)(src + lane*8);
        f4 f1 = *(const f4*)(src + lane*8 + 4);
        v = cvt8(f0, f1);
      }
      // k = lane*8+j -> kk=lane>>2, quad'=lane&3, j contiguous
      *(s8*)(xfc + (size_t)t*16384 + (lane>>2)*1024 + ((lane&3)*16 + bl)*16) = v;
    }
  }

  // ---- Phase A2: W_ih/W_hh slice -> register A-fragments (bf16) ----
  // slice row r = wave*16 + (lane&15); gate = r&3, unit_local = r>>2
  s8 wihf[16], whhf[16];
  {
    int r = wave*16 + n;
    int rowg = (r & 3)*512 + wg*16 + (r >> 2);
    const float* pih = W_ih + (size_t)rowg * DD + quad*8;
    const float* phh = W_hh + (size_t)rowg * HH + quad*8;
#pragma unroll
    for (int kk = 0; kk < 16; ++kk) {
      f4 a0 = *(const f4*)(pih + kk*32);
      f4 a1 = *(const f4*)(pih + kk*32 + 4);
      wihf[kk] = cvt8(a0, a1);
      f4 b0 = *(const f4*)(phh + kk*32);
      f4 b1 = *(const f4*)(phh + kk*32 + 4);
      whhf[kk] = cvt8(b0, b1);
    }
  }

  // ---- Phase A3: lane-private state. Lane updates unit u, batch n. ----
  const int u = wg*16 + wave*4 + quad;
  f4 biasv;
  biasv[0] = b_ih[0*512+u] + b_hh[0*512+u];        // i
  biasv[1] = b_ih[1*512+u] + b_hh[1*512+u];        // f
  biasv[2] = b_ih[2*512+u] + b_hh[2*512+u];        // g
  biasv[3] = b_ih[3*512+u] + b_hh[3*512+u];        // o
  float creg = 0.f, h0 = 0.f;
  if (n < 8) {
    creg = c_n[(size_t)(c*8 + n)*HH + u];
    h0   = h_n[(size_t)(c*8 + n)*HH + u];
  }
  const int hwoff = (u>>5)*1024 + ((((u>>3)&3)<<4) + n)*16 + (u&7)*2;
  *(short*)(hbuf + (size_t)c*16384 + hwoff) = f2bf(h0);   // buf 0 init

  float* outp = (n < 8) ? (out + (size_t)(c*8 + n)*SS*HH + u) : nullptr;

  cluster_barrier(cnt, 32u * 1);                   // phase A done

  // x-GEMM for t=0, pre-computed (2 chains for MFMA dep-latency)
  s8 xf[16];
  f4 accx, accx2 = {0.f,0.f,0.f,0.f};
#pragma unroll
  for (int kk = 0; kk < 16; ++kk)
    xf[kk] = *(const s8*)(xfc + kk*1024 + lane*16);
  accx = biasv;
#pragma unroll
  for (int kk = 0; kk < 8; ++kk)
    accx  = __builtin_amdgcn_mfma_f32_16x16x32_bf16(wihf[kk],   xf[kk],   accx,  0,0,0);
#pragma unroll
  for (int kk = 0; kk < 8; ++kk)
    accx2 = __builtin_amdgcn_mfma_f32_16x16x32_bf16(wihf[kk+8], xf[kk+8], accx2, 0,0,0);

  for (int t = 0; t < SS; ++t) {
    const char* hrd = hbuf + (size_t)(((t  )&1)*8 + c)*16384;
    char*       hwr = hbuf + (size_t)(((t+1)&1)*8 + c)*16384;

    s8 hf[16];
#pragma unroll
    for (int kk = 0; kk < 16; ++kk)
      hf[kk] = *(const s8*)(hrd + kk*1024 + lane*16);

    f4 acc = accx, acc2 = accx2;
#pragma unroll
    for (int kk = 0; kk < 8; ++kk)
      acc  = __builtin_amdgcn_mfma_f32_16x16x32_bf16(whhf[kk],   hf[kk],   acc,  0,0,0);
#pragma unroll
    for (int kk = 0; kk < 8; ++kk)
      acc2 = __builtin_amdgcn_mfma_f32_16x16x32_bf16(whhf[kk+8], hf[kk+8], acc2, 0,0,0);
    acc += acc2;

    // lane holds all 4 gates of (u, n): reg0=i, reg1=f, reg2=g, reg3=o
    float iv = sigm(acc[0]);
    float fv = sigm(acc[1]);
    float gv = tanh_f(acc[2]);
    float ov = sigm(acc[3]);
    creg = fv*creg + iv*gv;
    float hv = ov * tanh_f(creg);
    if (outp) outp[(size_t)t * HH] = hv;
    *(short*)(hwr + hwoff) = f2bf(hv);

    if (t < SS-1) {
      // prefetch x(t+1) and do its GEMM BEFORE the barrier — off critical path
#pragma unroll
      for (int kk = 0; kk < 16; ++kk)
        xf[kk] = *(const s8*)(xfc + (size_t)(t+1)*16384 + kk*1024 + lane*16);
      accx = biasv; accx2[0]=0.f; accx2[1]=0.f; accx2[2]=0.f; accx2[3]=0.f;
#pragma unroll
      for (int kk = 0; kk < 8; ++kk)
        accx  = __builtin_amdgcn_mfma_f32_16x16x32_bf16(wihf[kk],   xf[kk],   accx,  0,0,0);
#pragma unroll
      for (int kk = 0; kk < 8; ++kk)
        accx2 = __builtin_amdgcn_mfma_f32_16x16x32_bf16(wihf[kk+8], xf[kk+8], accx2, 0,0,0);

      cluster_barrier(cnt, 32u * (unsigned)(t + 2));
    }
  }
}

extern "C" void kernel_launch(void* const* d_in, const int* in_sizes, int n_in,
                              void* d_out, int out_size, void* d_ws, size_t ws_size,
                              hipStream_t stream) {
  const float* x    = (const float*)d_in[0];
  const float* emb  = (const float*)d_in[1];
  const float* h_n  = (const float*)d_in[2];
  const float* c_n  = (const float*)d_in[3];
  const float* W_ih = (const float*)d_in[4];
  const float* W_hh = (const float*)d_in[5];
  const float* b_ih = (const float*)d_in[6];
  const float* b_hh = (const float*)d_in[7];

  // zero the cluster barrier counters (ws is poisoned 0xAA each call)
  hipMemsetAsync(d_ws, 0, 1024, stream);

  lstm_kernel<<<dim3(256), dim3(256), 0, stream>>>(
      x, emb, h_n, c_n, W_ih, W_hh, b_ih, b_hh, (float*)d_out, (char*)d_ws);
}

// Round 2
// 2572.413 us; speedup vs baseline: 3.0848x; 3.0848x over previous
//
#include <hip/hip_runtime.h>
#include <cstdint>

// LSTM decoder: B=64, S=512, D=512, H=512.
// 8 clusters (blockIdx%8) x 32 WGs; cluster owns 8 batches. WG owns 16 hidden
// units (all 4 gates) with W_ih/W_hh slices in VGPRs as bf16 MFMA A-fragments.
// R2: all cross-WG h traffic via relaxed-agent atomics (sc1, L2-bypass) so the
// per-step barrier needs NO buffer_wbl2/buffer_inv. One heavy fence barrier
// after phase A covers the write-once cached x-fragment buffer.

#define SS 512
#define DD 512
#define HH 512

typedef __attribute__((ext_vector_type(8))) short s8;
typedef __attribute__((ext_vector_type(4))) float f4;

__device__ inline short f2bf(float f) {
  unsigned u = __float_as_uint(f);
  u += 0x7fffu + ((u >> 16) & 1u);   // RNE
  return (short)(u >> 16);
}

__device__ inline s8 cvt8(f4 a, f4 b) {
  s8 v;
  v[0]=f2bf(a[0]); v[1]=f2bf(a[1]); v[2]=f2bf(a[2]); v[3]=f2bf(a[3]);
  v[4]=f2bf(b[0]); v[5]=f2bf(b[1]); v[6]=f2bf(b[2]); v[7]=f2bf(b[3]);
  return v;
}

__device__ inline float sigm(float x)  { return 1.f / (1.f + __expf(-x)); }
__device__ inline float tanh_f(float x){ return 1.f - 2.f / (__expf(2.f*x) + 1.f); }

// Heavy barrier (used ONCE, after phase A): release fence (buffer_wbl2) makes
// the cached x-fragment stores visible; acquire load (buffer_inv) drops any
// stale lines (ws is reused across graph replays) in the reader's L2.
__device__ inline void heavy_barrier(unsigned* cnt, unsigned target) {
  __syncthreads();
  if (threadIdx.x == 0) {
    __threadfence();
    __hip_atomic_fetch_add(cnt, 1u, __ATOMIC_RELAXED, __HIP_MEMORY_SCOPE_AGENT);
    unsigned guard = 0;
    while (__hip_atomic_load(cnt, __ATOMIC_RELAXED, __HIP_MEMORY_SCOPE_AGENT) < target) {
      __builtin_amdgcn_s_sleep(2);
      if (++guard > 10000000u) break;
    }
  }
  __syncthreads();
  (void)__hip_atomic_load(cnt, __ATOMIC_ACQUIRE, __HIP_MEMORY_SCOPE_AGENT);
  __syncthreads();
}

// Light wait (per step): relaxed poll only — no cache maintenance.
__device__ inline void light_wait(unsigned* cnt, unsigned target) {
  if (threadIdx.x == 0) {
    unsigned guard = 0;
    while (__hip_atomic_load(cnt, __ATOMIC_RELAXED, __HIP_MEMORY_SCOPE_AGENT) < target) {
      __builtin_amdgcn_s_sleep(1);
      if (++guard > 10000000u) break;
    }
  }
  __syncthreads();
}

__device__ inline unsigned long long ldq(const void* p) {
  return __hip_atomic_load((const unsigned long long*)p,
                           __ATOMIC_RELAXED, __HIP_MEMORY_SCOPE_AGENT);
}
__device__ inline void stq(void* p, unsigned long long v) {
  __hip_atomic_store((unsigned long long*)p, v,
                     __ATOMIC_RELAXED, __HIP_MEMORY_SCOPE_AGENT);
}

__launch_bounds__(256, 1)
__global__ void lstm_kernel(const float* __restrict__ x,   const float* __restrict__ emb,
                            const float* __restrict__ h_n, const float* __restrict__ c_n,
                            const float* __restrict__ W_ih, const float* __restrict__ W_hh,
                            const float* __restrict__ b_ih, const float* __restrict__ b_hh,
                            float* __restrict__ out, char* __restrict__ ws)
{
  const int tid  = threadIdx.x;
  const int wave = tid >> 6, lane = tid & 63;
  const int quad = lane >> 4, n = lane & 15;       // n = batch column (8 real + 8 pad)
  const int c  = blockIdx.x & 7;                   // cluster (likely XCD-local, perf only)
  const int wg = blockIdx.x >> 3;                  // 0..31 within cluster

  unsigned* cnt = (unsigned*)(ws + (size_t)c * 128);
  char* hbuf  = ws + 1024;                         // [2][8 clusters][16KB] h fragments (sc1 traffic)
  char* xfrag = ws + 1024 + 2*8*16384;             // [8][512][16KB] x fragments (cached)
  char* xfc   = xfrag + (size_t)c * SS * 16384;

  // ---- Phase A1: (emb ++ x[:, :-1]) -> bf16 B-fragment layout, coalesced ----
  {
    int widc = wg*4 + wave;                        // 0..127 warps in cluster
    for (int item = widc; item < 8192; item += 128) {
      int t = item & 511, bl = item >> 9;          // bl = batch col slot 0..15
      s8 v = {0,0,0,0,0,0,0,0};
      if (bl < 8) {
        const float* src = (t == 0) ? (emb + (size_t)(c*8 + bl) * DD)
                                    : (x + ((size_t)(c*8 + bl) * SS + (t-1)) * DD);
        f4 f0 = *(const f4*)(src + lane*8);
        f4 f1 = *(const f4*)(src + lane*8 + 4);
        v = cvt8(f0, f1);
      }
      *(s8*)(xfc + (size_t)t*16384 + (lane>>2)*1024 + ((lane&3)*16 + bl)*16) = v;
    }
  }

  // ---- Phase A2: W_ih/W_hh slice -> register A-fragments (bf16) ----
  s8 wihf[16], whhf[16];
  {
    int r = wave*16 + n;                           // slice row
    int rowg = (r & 3)*512 + wg*16 + (r >> 2);     // gate-major row in W
    const float* pih = W_ih + (size_t)rowg * DD + quad*8;
    const float* phh = W_hh + (size_t)rowg * HH + quad*8;
#pragma unroll
    for (int kk = 0; kk < 16; ++kk) {
      f4 a0 = *(const f4*)(pih + kk*32);
      f4 a1 = *(const f4*)(pih + kk*32 + 4);
      wihf[kk] = cvt8(a0, a1);
      f4 b0 = *(const f4*)(phh + kk*32);
      f4 b1 = *(const f4*)(phh + kk*32 + 4);
      whhf[kk] = cvt8(b0, b1);
    }
  }

  // ---- Phase A3: lane-private state. Lane updates unit u, batch n. ----
  const int u = wg*16 + wave*4 + quad;
  f4 biasv;
  biasv[0] = b_ih[0*512+u] + b_hh[0*512+u];        // i
  biasv[1] = b_ih[1*512+u] + b_hh[1*512+u];        // f
  biasv[2] = b_ih[2*512+u] + b_hh[2*512+u];        // g
  biasv[3] = b_ih[3*512+u] + b_hh[3*512+u];        // o
  float creg = 0.f, h0 = 0.f;
  if (n < 8) {
    creg = c_n[(size_t)(c*8 + n)*HH + u];
    h0   = h_n[(size_t)(c*8 + n)*HH + u];
  }
  // 8B-packed h store offset for lanes 0..15 (n = lane): covers quads 0..3
  const int u0 = wg*16 + wave*4;
  const int hw8off = (u0>>5)*1024 + ((u0>>3)&3)*256 + lane*16 + (u0&7)*2;

  float* outp = (n < 8) ? (out + (size_t)(c*8 + n)*SS*HH + u) : nullptr;

  // h0 -> buf 0 via packed sc1 stores
  {
    int sv = (int)(unsigned short)f2bf(h0);
    int p2 = sv | (__shfl_xor(sv, 16) << 16);
    int p4 = __shfl_xor(p2, 32);
    unsigned long long packed = (unsigned)p2 | ((unsigned long long)(unsigned)p4 << 32);
    if (lane < 16) stq(hbuf + (size_t)c*16384 + hw8off, packed);
  }

  heavy_barrier(cnt, 32u);                         // phase A done; counter == 32

  // x-GEMM for t=0 (xfrag is cached + coherent after heavy barrier)
  s8 xf[16];
  f4 accx, accx2 = {0.f,0.f,0.f,0.f};
#pragma unroll
  for (int kk = 0; kk < 16; ++kk)
    xf[kk] = *(const s8*)(xfc + kk*1024 + lane*16);
  accx = biasv;
#pragma unroll
  for (int kk = 0; kk < 8; ++kk)
    accx  = __builtin_amdgcn_mfma_f32_16x16x32_bf16(wihf[kk],   xf[kk],   accx,  0,0,0);
#pragma unroll
  for (int kk = 0; kk < 8; ++kk)
    accx2 = __builtin_amdgcn_mfma_f32_16x16x32_bf16(wihf[kk+8], xf[kk+8], accx2, 0,0,0);

  for (int t = 0; t < SS; ++t) {
    light_wait(cnt, 32u * (unsigned)(t + 1));      // h_t visible at coherent point

    const char* hrd = hbuf + (size_t)(((t  )&1)*8 + c)*16384;
    char*       hwr = hbuf + (size_t)(((t+1)&1)*8 + c)*16384;

    // h fragments: 8B sc1 loads (bypass non-coherent L1/L2)
    s8 hf[16];
#pragma unroll
    for (int kk = 0; kk < 16; ++kk) {
      union { unsigned long long q[2]; s8 v; } tmp;
      const char* p = hrd + kk*1024 + lane*16;
      tmp.q[0] = ldq(p);
      tmp.q[1] = ldq(p + 8);
      hf[kk] = tmp.v;
    }

    f4 acc = accx, acc2 = accx2;
#pragma unroll
    for (int kk = 0; kk < 8; ++kk)
      acc  = __builtin_amdgcn_mfma_f32_16x16x32_bf16(whhf[kk],   hf[kk],   acc,  0,0,0);
#pragma unroll
    for (int kk = 0; kk < 8; ++kk)
      acc2 = __builtin_amdgcn_mfma_f32_16x16x32_bf16(whhf[kk+8], hf[kk+8], acc2, 0,0,0);
    acc += acc2;

    // lane holds all 4 gates of (u, n): reg0=i, reg1=f, reg2=g, reg3=o
    float iv = sigm(acc[0]);
    float fv = sigm(acc[1]);
    float gv = tanh_f(acc[2]);
    float ov = sigm(acc[3]);
    creg = fv*creg + iv*gv;
    float hv = ov * tanh_f(creg);
    if (outp) outp[(size_t)t * HH] = hv;

    // pack 4 quads' h into 8B, lanes 0..15 store (sc1)
    {
      int sv = (int)(unsigned short)f2bf(hv);
      int p2 = sv | (__shfl_xor(sv, 16) << 16);
      int p4 = __shfl_xor(p2, 32);
      unsigned long long packed = (unsigned)p2 | ((unsigned long long)(unsigned)p4 << 32);
      if (lane < 16) stq(hwr + hw8off, packed);
    }

    if (t < SS-1) {
      __syncthreads();                             // drains vmcnt: h stores complete
      if (tid == 0)
        __hip_atomic_fetch_add(cnt, 1u, __ATOMIC_RELAXED, __HIP_MEMORY_SCOPE_AGENT);

      // x-GEMM for t+1 AFTER arrive — hides in other WGs' barrier slack
#pragma unroll
      for (int kk = 0; kk < 16; ++kk)
        xf[kk] = *(const s8*)(xfc + (size_t)(t+1)*16384 + kk*1024 + lane*16);
      accx = biasv; accx2[0]=0.f; accx2[1]=0.f; accx2[2]=0.f; accx2[3]=0.f;
#pragma unroll
      for (int kk = 0; kk < 8; ++kk)
        accx  = __builtin_amdgcn_mfma_f32_16x16x32_bf16(wihf[kk],   xf[kk],   accx,  0,0,0);
#pragma unroll
      for (int kk = 0; kk < 8; ++kk)
        accx2 = __builtin_amdgcn_mfma_f32_16x16x32_bf16(wihf[kk+8], xf[kk+8], accx2, 0,0,0);
    }
  }
}

extern "C" void kernel_launch(void* const* d_in, const int* in_sizes, int n_in,
                              void* d_out, int out_size, void* d_ws, size_t ws_size,
                              hipStream_t stream) {
  const float* x    = (const float*)d_in[0];
  const float* emb  = (const float*)d_in[1];
  const float* h_n  = (const float*)d_in[2];
  const float* c_n  = (const float*)d_in[3];
  const float* W_ih = (const float*)d_in[4];
  const float* W_hh = (const float*)d_in[5];
  const float* b_ih = (const float*)d_in[6];
  const float* b_hh = (const float*)d_in[7];

  hipMemsetAsync(d_ws, 0, 1024, stream);           // cluster barrier counters

  lstm_kernel<<<dim3(256), dim3(256), 0, stream>>>(
      x, emb, h_n, c_n, W_ih, W_hh, b_ih, b_hh, (float*)d_out, (char*)d_ws);
}

// Round 4
// 1683.610 us; speedup vs baseline: 4.7133x; 1.5279x over previous
//
#include <hip/hip_runtime.h>
#include <cstdint>

// LSTM decoder: B=64, S=512, D=512, H=512.
// 8 clusters (blockIdx%8) x 32 WGs; cluster owns 8 batches. WG owns 16 hidden
// units (all 4 gates); W_ih/W_hh slices live in VGPRs as bf16 MFMA A-frags.
// R4: proven agent-scope relaxed atomics ONLY (no sc0 cache bets). Wins vs R2:
// flag-array barrier (no 32-deep fetch_add serialization), compact 8-col
// h/x buffers (half the IC traffic), LDS-transposed coalesced out stores
// placed after the flag store, poll without s_sleep.

#define SS 512
#define DD 512
#define HH 512

typedef __attribute__((ext_vector_type(8))) short s8;
typedef __attribute__((ext_vector_type(4))) float f4;

__device__ inline short f2bf(float f) {
  unsigned u = __float_as_uint(f);
  u += 0x7fffu + ((u >> 16) & 1u);   // RNE
  return (short)(u >> 16);
}

__device__ inline s8 cvt8(f4 a, f4 b) {
  s8 v;
  v[0]=f2bf(a[0]); v[1]=f2bf(a[1]); v[2]=f2bf(a[2]); v[3]=f2bf(a[3]);
  v[4]=f2bf(b[0]); v[5]=f2bf(b[1]); v[6]=f2bf(b[2]); v[7]=f2bf(b[3]);
  return v;
}

__device__ inline float sigm(float x)  { return 1.f / (1.f + __expf(-x)); }
__device__ inline float tanh_f(float x){ return 1.f - 2.f / (__expf(2.f*x) + 1.f); }

__device__ inline void stq_agent(void* p, unsigned long long v) {
  __hip_atomic_store((unsigned long long*)p, v, __ATOMIC_RELAXED, __HIP_MEMORY_SCOPE_AGENT);
}
__device__ inline unsigned long long ldq_agent(const void* p) {
  return __hip_atomic_load((const unsigned long long*)p, __ATOMIC_RELAXED, __HIP_MEMORY_SCOPE_AGENT);
}
__device__ inline void st4_agent(unsigned* p, unsigned v) {
  __hip_atomic_store(p, v, __ATOMIC_RELAXED, __HIP_MEMORY_SCOPE_AGENT);
}
__device__ inline unsigned ld4_agent(const unsigned* p) {
  return __hip_atomic_load(p, __ATOMIC_RELAXED, __HIP_MEMORY_SCOPE_AGENT);
}
__device__ inline void drain_vm() {
  asm volatile("s_waitcnt vmcnt(0)" ::: "memory");
}

// Heavy barrier (ONCE, after phase A): release fence + counter + acquire.
__device__ inline void heavy_barrier(unsigned* cnt, unsigned target) {
  drain_vm();
  __syncthreads();
  if (threadIdx.x == 0) {
    __threadfence();
    __hip_atomic_fetch_add(cnt, 1u, __ATOMIC_RELAXED, __HIP_MEMORY_SCOPE_AGENT);
    unsigned guard = 0;
    while (__hip_atomic_load(cnt, __ATOMIC_RELAXED, __HIP_MEMORY_SCOPE_AGENT) < target) {
      __builtin_amdgcn_s_sleep(2);
      if (++guard > 10000000u) break;
    }
  }
  __syncthreads();
  (void)__hip_atomic_load(cnt, __ATOMIC_ACQUIRE, __HIP_MEMORY_SCOPE_AGENT);
  __syncthreads();
}

__launch_bounds__(256, 1)
__global__ void lstm_kernel(const float* __restrict__ x,   const float* __restrict__ emb,
                            const float* __restrict__ h_n, const float* __restrict__ c_n,
                            const float* __restrict__ W_ih, const float* __restrict__ W_hh,
                            const float* __restrict__ b_ih, const float* __restrict__ b_hh,
                            float* __restrict__ out, char* __restrict__ ws)
{
  const int tid  = threadIdx.x;
  const int wave = tid >> 6, lane = tid & 63;
  const int quad = lane >> 4, n = lane & 15;       // n = batch column (8 real + 8 pad)
  const int c  = blockIdx.x & 7;                   // cluster
  const int wg = blockIdx.x >> 3;                  // 0..31 within cluster

  unsigned* cnt   = (unsigned*)(ws + (size_t)c * 128);
  unsigned* flags = (unsigned*)(ws + 1024 + (size_t)c * 128);   // 32 x u32
  char*     hbuf  = ws + 4096;                                  // [2][8][8KB] compact h
  char*     xfrag = ws + 4096 + 2*8*8192;                       // [8][512][8KB] compact x
  char*     xfc   = xfrag + (size_t)c * ((size_t)SS * 8192);

  __shared__ float lout[2][128];

  // ---- Phase A1: (emb ++ x[:, :-1]) -> compact bf16 B-frag layout ----
  {
    int widc = wg*4 + wave;                        // 0..127 warps in cluster
    for (int item = widc; item < 4096; item += 128) {
      int t = item & 511, bl = item >> 9;          // bl 0..7 (real batches only)
      const float* src = (t == 0) ? (emb + (size_t)(c*8 + bl) * DD)
                                  : (x + ((size_t)(c*8 + bl) * SS + (t-1)) * DD);
      f4 f0 = *(const f4*)(src + lane*8);
      f4 f1 = *(const f4*)(src + lane*8 + 4);
      s8 v = cvt8(f0, f1);
      // element (k=lane*8+j, col=bl) at (k>>5)*512 + ((k>>3)&3)*128 + bl*16 + (k&7)*2
      *(s8*)(xfc + (size_t)t*8192 + (lane>>2)*512 + (lane&3)*128 + bl*16) = v;
    }
  }

  // ---- Phase A2: W_ih/W_hh slices -> register A-fragments (bf16) ----
  s8 wihf[16], whhf[16];
  {
    int r = wave*16 + n;                           // row in WG's 64-row slice
    int rowg = (r & 3)*512 + wg*16 + (r >> 2);     // gate-major row in W
    const float* pih = W_ih + (size_t)rowg * DD + quad*8;
    const float* phh = W_hh + (size_t)rowg * HH + quad*8;
#pragma unroll
    for (int kk = 0; kk < 16; ++kk) {
      f4 a0 = *(const f4*)(pih + kk*32);
      f4 a1 = *(const f4*)(pih + kk*32 + 4);
      wihf[kk] = cvt8(a0, a1);
      f4 b0 = *(const f4*)(phh + kk*32);
      f4 b1 = *(const f4*)(phh + kk*32 + 4);
      whhf[kk] = cvt8(b0, b1);
    }
  }

  // ---- Phase A3: lane-private state. Lane updates unit u, batch n. ----
  const int u = wg*16 + wave*4 + quad;
  f4 biasv;
  biasv[0] = b_ih[0*512+u] + b_hh[0*512+u];        // i
  biasv[1] = b_ih[1*512+u] + b_hh[1*512+u];        // f
  biasv[2] = b_ih[2*512+u] + b_hh[2*512+u];        // g
  biasv[3] = b_ih[3*512+u] + b_hh[3*512+u];        // o
  float creg = 0.f, h0 = 0.f;
  if (n < 8) {
    creg = c_n[(size_t)(c*8 + n)*HH + u];
    h0   = h_n[(size_t)(c*8 + n)*HH + u];
  }
  // compact h store base for this wave's 4 units (u0..u0+3), col = lane (0..7)
  const int u0 = wg*16 + wave*4;
  const int hsoff = (u0>>5)*512 + ((u0>>3)&3)*128 + (u0&7)*2;

  // h0 -> parity-0 buffer (packed 4 units x bf16 = 8B, lanes 0..7 store)
  {
    int sv = (int)(unsigned short)f2bf(h0);
    int p2 = sv | (__shfl_xor(sv, 16) << 16);      // quads 0,1 of col n=lane
    int p4 = __shfl_xor(p2, 32);                   // quads 2,3
    unsigned long long packed = (unsigned)p2 | ((unsigned long long)(unsigned)p4 << 32);
    if (lane < 8) stq_agent(hbuf + (size_t)c*8192 + hsoff + lane*16, packed);
  }

  heavy_barrier(cnt, 32u);                         // phase A visible everywhere

  const s8 zero8 = {0,0,0,0,0,0,0,0};
  s8 xf[16], hf[16];
#pragma unroll
  for (int kk = 0; kk < 16; ++kk) { xf[kk] = zero8; hf[kk] = zero8; }  // pad lanes stay 0

  // x-GEMM for t=0 (xfrag cached, coherent after heavy barrier)
  f4 accx = biasv, accx2 = {0.f,0.f,0.f,0.f};
  if (n < 8) {
    const char* xb = xfc + quad*128 + n*16;
#pragma unroll
    for (int kk = 0; kk < 16; ++kk)
      xf[kk] = *(const s8*)(xb + kk*512);
  }
#pragma unroll
  for (int kk = 0; kk < 8; ++kk)
    accx  = __builtin_amdgcn_mfma_f32_16x16x32_bf16(wihf[kk],   xf[kk],   accx,  0,0,0);
#pragma unroll
  for (int kk = 0; kk < 8; ++kk)
    accx2 = __builtin_amdgcn_mfma_f32_16x16x32_bf16(wihf[kk+8], xf[kk+8], accx2, 0,0,0);

  float* const outb = out + (size_t)(c*8)*SS*HH + wg*16;

  for (int t = 0; t < SS; ++t) {
    // ---- wait for h_t (flags monotone; t=0 ready via heavy barrier) ----
    if (t > 0) {
      if (tid < 64) {                              // wave 0 polls, lanes mirror 32 flags
        const unsigned* fp = flags + (lane & 31);
        unsigned guard = 0; bool ok;
        do {
          ok = (ld4_agent(fp) >= (unsigned)t);
          if (++guard > 100000u) break;            // anti-hang failsafe
        } while (!__all(ok));
      }
      __syncthreads();
    }

    const char* hrd = hbuf + (size_t)(((t  )&1)*8 + c)*8192;
    char*       hwr = hbuf + (size_t)(((t+1)&1)*8 + c)*8192;

    // ---- h fragments: 8B agent loads, compact (real cols only) ----
    if (n < 8) {
      const char* b0 = hrd + quad*128 + n*16;
      union { unsigned long long qq[2]; s8 v; } tmp;
#pragma unroll
      for (int kk = 0; kk < 16; ++kk) {
        tmp.qq[0] = ldq_agent(b0 + kk*512);
        tmp.qq[1] = ldq_agent(b0 + kk*512 + 8);
        hf[kk] = tmp.v;
      }
    }

    f4 acc = accx, acc2 = accx2;
#pragma unroll
    for (int kk = 0; kk < 8; ++kk)
      acc  = __builtin_amdgcn_mfma_f32_16x16x32_bf16(whhf[kk],   hf[kk],   acc,  0,0,0);
#pragma unroll
    for (int kk = 0; kk < 8; ++kk)
      acc2 = __builtin_amdgcn_mfma_f32_16x16x32_bf16(whhf[kk+8], hf[kk+8], acc2, 0,0,0);
    acc += acc2;

    // lane holds all 4 gates of (u, n): reg0=i, reg1=f, reg2=g, reg3=o
    float iv = sigm(acc[0]);
    float fv = sigm(acc[1]);
    float gv = tanh_f(acc[2]);
    float ov = sigm(acc[3]);
    creg = fv*creg + iv*gv;
    float hv = ov * tanh_f(creg);

    if (n < 8) lout[t&1][n*16 + wave*4 + quad] = hv;   // out transpose staging

    // ---- publish h_{t+1} (packed 8B agent stores, lanes 0..7) ----
    if (t < SS-1) {
      int sv = (int)(unsigned short)f2bf(hv);
      int p2 = sv | (__shfl_xor(sv, 16) << 16);
      int p4 = __shfl_xor(p2, 32);
      unsigned long long packed = (unsigned)p2 | ((unsigned long long)(unsigned)p4 << 32);
      if (lane < 8) stq_agent(hwr + hsoff + lane*16, packed);
    }

    drain_vm();                                    // h stores acked at coherent point
    __syncthreads();                               // whole WG's stores drained

    if (t < SS-1 && tid == 0)
      st4_agent(flags + wg, (unsigned)(t + 1));    // signal: h_{t+1} ready

    // ---- coalesced out store (after flag — off critical path) ----
    if (tid < 128) {
      int n2 = tid >> 4, ul = tid & 15;
      outb[((size_t)n2*SS + t)*HH + ul] = lout[t&1][n2*16 + ul];
    }

    // ---- x-GEMM for t+1 (hides in other WGs' barrier slack) ----
    if (t < SS-1) {
      if (n < 8) {
        const char* xb = xfc + (size_t)(t+1)*8192 + quad*128 + n*16;
#pragma unroll
        for (int kk = 0; kk < 16; ++kk)
          xf[kk] = *(const s8*)(xb + kk*512);
      }
      accx = biasv; accx2[0]=0.f; accx2[1]=0.f; accx2[2]=0.f; accx2[3]=0.f;
#pragma unroll
      for (int kk = 0; kk < 8; ++kk)
        accx  = __builtin_amdgcn_mfma_f32_16x16x32_bf16(wihf[kk],   xf[kk],   accx,  0,0,0);
#pragma unroll
      for (int kk = 0; kk < 8; ++kk)
        accx2 = __builtin_amdgcn_mfma_f32_16x16x32_bf16(wihf[kk+8], xf[kk+8], accx2, 0,0,0);
    }
  }
}

extern "C" void kernel_launch(void* const* d_in, const int* in_sizes, int n_in,
                              void* d_out, int out_size, void* d_ws, size_t ws_size,
                              hipStream_t stream) {
  const float* x    = (const float*)d_in[0];
  const float* emb  = (const float*)d_in[1];
  const float* h_n  = (const float*)d_in[2];
  const float* c_n  = (const float*)d_in[3];
  const float* W_ih = (const float*)d_in[4];
  const float* W_hh = (const float*)d_in[5];
  const float* b_ih = (const float*)d_in[6];
  const float* b_hh = (const float*)d_in[7];

  hipMemsetAsync(d_ws, 0, 2048, stream);           // barrier counters + flag arrays

  lstm_kernel<<<dim3(256), dim3(256), 0, stream>>>(
      x, emb, h_n, c_n, W_ih, W_hh, b_ih, b_hh, (float*)d_out, (char*)d_ws);
}